// Round 7
// baseline (661.522 us; speedup 1.0000x reference)
//
#include <hip/hip_runtime.h>

#define E_DIM  256
#define NC     1024
#define BM     128
#define NT     512
#define MARGIN 0.02f

typedef short  bf16x8 __attribute__((ext_vector_type(8)));
typedef float  f32x4  __attribute__((ext_vector_type(4)));

// split f32 into bf16 hi + bf16 lo (both round-to-nearest-even)
static __device__ __forceinline__ void split2(float x, short& hi, short& lo) {
    const unsigned u  = __float_as_uint(x);
    const unsigned hb = (u + 0x7FFFu + ((u >> 16) & 1u)) >> 16;
    hi = (short)hb;
    const float l = x - __uint_as_float(hb << 16);   // exact in f32
    const unsigned u2 = __float_as_uint(l);
    lo = (short)((u2 + 0x7FFFu + ((u2 >> 16) & 1u)) >> 16);
}

// value with low 10 mantissa bits <- (1023 - idx): fmax = value-compare with
// first-index tie-break for positive gaps; perturbation << MARGIN.
static __device__ __forceinline__ float mkey(float v, unsigned il) {
    return __uint_as_float((__float_as_uint(v) & 0xFFFFFC00u) | il);
}

// async 16B global -> LDS (wave-uniform LDS base + lane*16)
static __device__ __forceinline__ void gload16(const void* g, void* l) {
    __builtin_amdgcn_global_load_lds(
        (const __attribute__((address_space(1))) unsigned int*)g,
        (__attribute__((address_space(3))) unsigned int*)l, 16, 0, 0);
}

// ---- prep: emb (f32) -> 64 chunk images (16KB each) of bf16 hi/lo ----
// chunk gc = tile*8 + kc covers codes [tile*128,+128) x k [kc*32,+32).
// Row r = 128 B = 8 slots of 16 B. Physical slot s holds logical slot
// s ^ (r&7), where logical 0..3 = hi k-groups, 4..7 = lo k-groups.
__global__ __launch_bounds__(256) void vq_prep(
    const float* __restrict__ emb, short* __restrict__ img)
{
    const int t    = blockIdx.x * 256 + threadIdx.x;   // 0..32767
    const int kg   = t & 3;             // k-group of 8 within chunk
    const int r    = (t >> 2) & 127;    // code row within tile
    const int kc   = (t >> 9) & 7;      // k chunk of 32
    const int tile = t >> 12;           // 0..7
    const float* src = &emb[(size_t)(tile * 128 + r) * E_DIM + kc * 32 + kg * 8];
    const f32x4 x0 = *reinterpret_cast<const f32x4*>(&src[0]);
    const f32x4 x1 = *reinterpret_cast<const f32x4*>(&src[4]);
    bf16x8 h, l; short hh, ll;
#pragma unroll
    for (int j = 0; j < 4; ++j) { split2(x0[j], hh, ll); h[j]     = hh; l[j]     = ll; }
#pragma unroll
    for (int j = 0; j < 4; ++j) { split2(x1[j], hh, ll); h[4 + j] = hh; l[4 + j] = ll; }
    const int hs = kg ^ (r & 7);          // physical slot of hi group
    const int ls = (4 + kg) ^ (r & 7);    // physical slot of lo group
    short* rowp = &img[(size_t)(tile * 8 + kc) * 8192 + r * 64];
    *reinterpret_cast<bf16x8*>(&rowp[hs * 8]) = h;
    *reinterpret_cast<bf16x8*>(&rowp[ls * 8]) = l;
}

__global__ __launch_bounds__(NT, 2) void vq_kernel(
    const float* __restrict__ z, const float* __restrict__ emb,
    const short* __restrict__ img, float* __restrict__ zq,
    float* __restrict__ loss, float* __restrict__ idxf, float invN)
{
    __shared__ char  Bs[3][16384];
    __shared__ float topk[2][BM][2];
    __shared__ int   rowIdx[BM];
    __shared__ int   ambList[BM];
    __shared__ int   ambCnt;
    __shared__ float zs[E_DIM];
    __shared__ float redV[8];
    __shared__ int   redI[8];

    const int tid  = threadIdx.x;
    const int lane = tid & 63;
    const int w    = tid >> 6;       // wave 0..7
    const int wm   = w >> 1;         // row group 0..3 (32 rows each)
    const int wn   = w & 1;          // col half 0..1 (64 cols each)
    const int l15  = lane & 15;
    const int l4   = lane >> 4;
    const int rb   = blockIdx.x * BM;

    // prologue: stage chunks 0 and 1 (their loads are the OLDEST vmem ops)
#pragma unroll
    for (int c = 0; c < 2; ++c)
#pragma unroll
        for (int q = 0; q < 2; ++q) {
            const int off = (q * 8 + w) * 1024;
            gload16((const char*)img + c * 16384 + off + (lane << 4), &Bs[c][off]);
        }

    // ---- A (z) fragments -> registers as bf16 hi/lo; z read ONCE ----
    // (these loads are fully consumed below, so they drain before the loop)
    bf16x8 a_hi[2][8], a_lo[2][8];
#pragma unroll
    for (int m = 0; m < 2; ++m) {
        const float* zp = &z[(size_t)(rb + wm * 32 + m * 16 + l15) * E_DIM + l4 * 8];
#pragma unroll
        for (int s = 0; s < 8; ++s) {
            const f32x4 x0 = *reinterpret_cast<const f32x4*>(&zp[s * 32]);
            const f32x4 x1 = *reinterpret_cast<const f32x4*>(&zp[s * 32 + 4]);
            bf16x8 h, l; short hh, ll;
#pragma unroll
            for (int j = 0; j < 4; ++j) { split2(x0[j], hh, ll); h[j]   = hh; l[j]   = ll; }
#pragma unroll
            for (int j = 0; j < 4; ++j) { split2(x1[j], hh, ll); h[4+j] = hh; l[4+j] = ll; }
            a_hi[m][s] = h; a_lo[m][s] = l;
        }
    }

    float k1[2][4], k2[2][4];
#pragma unroll
    for (int m = 0; m < 2; ++m)
#pragma unroll
        for (int j = 0; j < 4; ++j) { k1[m][j] = -3.0e38f; k2[m][j] = -3.0e38f; }

    // B-fragment byte offsets within a chunk image (loop-invariant)
    int offH[4], offL[4];
#pragma unroll
    for (int n = 0; n < 4; ++n) {
        const int row = wn * 64 + n * 16 + l15;
        const int sw  = (row & 7) << 4;
        offH[n] = row * 128 + ((l4 << 4) ^ sw);
        offL[n] = row * 128 + (((4 + l4) << 4) ^ sw);
    }

    // chunk 0 resident (chunk 1's 2 loads may stay in flight), then barrier
    asm volatile("s_waitcnt vmcnt(2)" ::: "memory");
    __builtin_amdgcn_s_barrier();

    int cur = 0, nx2 = 2;    // compute buffer / stage-2-ahead buffer
    for (int tile = 0; tile < 8; ++tile) {
        f32x4 acc[2][4];
        const f32x4 zz = {0.f, 0.f, 0.f, 0.f};
#pragma unroll
        for (int m = 0; m < 2; ++m)
#pragma unroll
            for (int n = 0; n < 4; ++n) acc[m][n] = zz;

#pragma unroll
        for (int kc = 0; kc < 8; ++kc) {
            const int gc = tile * 8 + kc;
            if (gc <= 61) {                       // issue stage of chunk gc+2
                const char* g = (const char*)img + (size_t)(gc + 2) * 16384;
                char* const db = Bs[nx2];
#pragma unroll
                for (int q = 0; q < 2; ++q) {
                    const int off = (q * 8 + w) * 1024;
                    gload16(g + off + (lane << 4), db + off);
                }
            }
            const char* bc = Bs[cur];
            bf16x8 bh[4], bl[4];
#pragma unroll
            for (int n = 0; n < 4; ++n) {
                bh[n] = *reinterpret_cast<const bf16x8*>(&bc[offH[n]]);
                bl[n] = *reinterpret_cast<const bf16x8*>(&bc[offL[n]]);
            }
#pragma unroll
            for (int m = 0; m < 2; ++m) {
                const bf16x8 ah = a_hi[m][kc];
                const bf16x8 al = a_lo[m][kc];
#pragma unroll
                for (int n = 0; n < 4; ++n) {
                    acc[m][n] = __builtin_amdgcn_mfma_f32_16x16x32_bf16(ah, bh[n], acc[m][n], 0, 0, 0);
                    acc[m][n] = __builtin_amdgcn_mfma_f32_16x16x32_bf16(ah, bl[n], acc[m][n], 0, 0, 0);
                    acc[m][n] = __builtin_amdgcn_mfma_f32_16x16x32_bf16(al, bh[n], acc[m][n], 0, 0, 0);
                }
            }
            // counted wait: own chunk gc+1 loads done; gc+2's 2 stay in flight
            if (gc < 62) asm volatile("s_waitcnt vmcnt(2)" ::: "memory");
            else         asm volatile("s_waitcnt vmcnt(0)" ::: "memory");
            __builtin_amdgcn_s_barrier();
            cur = (cur == 2) ? 0 : cur + 1;
            nx2 = (nx2 == 2) ? 0 : nx2 + 1;
        }

        // fold tile into running top-2 mangled keys (register-only)
        const int colbase = tile * 128 + wn * 64 + l15;
        unsigned il[4];
#pragma unroll
        for (int n = 0; n < 4; ++n) il[n] = (unsigned)(1023 - (colbase + n * 16));
#pragma unroll
        for (int m = 0; m < 2; ++m)
#pragma unroll
            for (int j = 0; j < 4; ++j) {
                const float a0 = acc[m][0][j], a1 = acc[m][1][j];
                const float a2 = acc[m][2][j], a3 = acc[m][3][j];
                const float q = fmaxf(fmaxf(a0, a1), fmaxf(a2, a3));
                if (q > k2[m][j]) {
                    float x, t;
                    x = mkey(a0, il[0]); t = fminf(k1[m][j], x);
                    k1[m][j] = fmaxf(k1[m][j], x); k2[m][j] = fmaxf(k2[m][j], t);
                    x = mkey(a1, il[1]); t = fminf(k1[m][j], x);
                    k1[m][j] = fmaxf(k1[m][j], x); k2[m][j] = fmaxf(k2[m][j], t);
                    x = mkey(a2, il[2]); t = fminf(k1[m][j], x);
                    k1[m][j] = fmaxf(k1[m][j], x); k2[m][j] = fmaxf(k2[m][j], t);
                    x = mkey(a3, il[3]); t = fminf(k1[m][j], x);
                    k1[m][j] = fmaxf(k1[m][j], x); k2[m][j] = fmaxf(k2[m][j], t);
                }
            }
    }

    // reduce top-2 across the 16 lanes sharing each row
#pragma unroll
    for (int m = 0; m < 2; ++m)
#pragma unroll
        for (int j = 0; j < 4; ++j) {
            float a = k1[m][j], b = k2[m][j];
#pragma unroll
            for (int s = 1; s < 16; s <<= 1) {
                const float oa = __shfl_xor(a, s, 64);
                const float ob = __shfl_xor(b, s, 64);
                const float t  = fminf(a, oa);
                a = fmaxf(a, oa);
                b = fmaxf(fmaxf(b, ob), t);
            }
            if (l15 == 0) {
                const int row = wm * 32 + m * 16 + l4 * 4 + j;
                topk[wn][row][0] = a;
                topk[wn][row][1] = b;
            }
        }
    if (tid == 0) ambCnt = 0;
    __syncthreads();

    if (tid < BM) {
        float a = topk[0][tid][0], b = topk[0][tid][1];
        const float oa = topk[1][tid][0], ob = topk[1][tid][1];
        const float t  = fminf(a, oa);
        a = fmaxf(a, oa);
        b = fmaxf(fmaxf(b, ob), t);
        const unsigned ub = __float_as_uint(a);
        rowIdx[tid] = 1023 - (int)(ub & 1023u);
        const float v1 = __uint_as_float(ub & 0xFFFFFC00u);
        const float v2 = __uint_as_float(__float_as_uint(b) & 0xFFFFFC00u);
        if (v1 - v2 <= MARGIN) {                 // ambiguous -> exact in-block rescan
            const int p = atomicAdd(&ambCnt, 1); // capacity == BM, cannot overflow
            ambList[p] = tid;
        }
    }
    __syncthreads();

    // exact f32 rescan of flagged rows (rare)
    const int nAmb = ambCnt;
    for (int ai = 0; ai < nAmb; ++ai) {
        const int row = ambList[ai];
        if (tid < 64)
            *reinterpret_cast<f32x4*>(&zs[tid * 4]) =
                *reinterpret_cast<const f32x4*>(&z[(size_t)(rb + row) * E_DIM + tid * 4]);
        __syncthreads();
        float best = -3.0e38f; int bidx = 0;
#pragma unroll
        for (int cc = 0; cc < 2; ++cc) {
            const int c = tid * 2 + cc;          // ascending within thread
            const float* ep = &emb[(size_t)c * E_DIM];
            float p = 0.f;
#pragma unroll 8
            for (int qd = 0; qd < 64; ++qd) {
                const f32x4 e4 = *reinterpret_cast<const f32x4*>(&ep[qd * 4]);
                const f32x4 z4 = *reinterpret_cast<const f32x4*>(&zs[qd * 4]);
                p = fmaf(z4[0], e4[0], p); p = fmaf(z4[1], e4[1], p);
                p = fmaf(z4[2], e4[2], p); p = fmaf(z4[3], e4[3], p);
            }
            if (p > best) { best = p; bidx = c; }
        }
#pragma unroll
        for (int s = 1; s < 64; s <<= 1) {
            const float ov = __shfl_xor(best, s, 64);
            const int   oi = __shfl_xor(bidx, s, 64);
            if (ov > best || (ov == best && oi < bidx)) { best = ov; bidx = oi; }
        }
        if (lane == 0) { redV[w] = best; redI[w] = bidx; }
        __syncthreads();
        if (tid == 0) {
            float bb = redV[0]; int bi = redI[0];
#pragma unroll
            for (int ww = 1; ww < 8; ++ww)
                if (redV[ww] > bb) { bb = redV[ww]; bi = redI[ww]; }
            rowIdx[row] = bi;                    // zq & idx both come from rowIdx
        }
        __syncthreads();
    }

    // epilogue: gather emb[idx] -> zq, SSE, idx output, loss atomics
    float sse = 0.f;
#pragma unroll
    for (int i = 0; i < 16; ++i) {
        const int f   = i * NT + tid;            // 8192 quads of the 128x256 tile
        const int row = f >> 6;
        const int kq  = f & 63;
        const int idx = rowIdx[row];
        const f32x4 e4 = *reinterpret_cast<const f32x4*>(&emb[(size_t)idx * E_DIM + kq * 4]);
        const f32x4 z4 = *reinterpret_cast<const f32x4*>(&z[(size_t)(rb + row) * E_DIM + kq * 4]);
        const float d0 = e4[0] - z4[0], d1 = e4[1] - z4[1];
        const float d2 = e4[2] - z4[2], d3 = e4[3] - z4[3];
        sse += d0 * d0 + d1 * d1 + d2 * d2 + d3 * d3;
        *reinterpret_cast<f32x4*>(&zq[(size_t)(rb + row) * E_DIM + kq * 4]) = e4;
    }
    if (tid < BM) idxf[rb + tid] = (float)rowIdx[tid];
#pragma unroll
    for (int s = 1; s < 64; s <<= 1) sse += __shfl_xor(sse, s, 64);
    if (lane == 0) redV[w] = sse;
    __syncthreads();
    if (tid == 0) {
        float t = 0.f;
#pragma unroll
        for (int ww = 0; ww < 8; ++ww) t += redV[ww];
        atomicAdd(&loss[0], t * invN);
        atomicAdd(&loss[1], 0.25f * t * invN);
    }
}

extern "C" void kernel_launch(void* const* d_in, const int* in_sizes, int n_in,
                              void* d_out, int out_size, void* d_ws, size_t ws_size,
                              hipStream_t stream) {
    const float* z   = (const float*)d_in[0];
    const float* emb = (const float*)d_in[1];
    const int zsz    = in_sizes[0];        // 33554432
    const int nrows  = zsz / E_DIM;        // 131072

    float* out  = (float*)d_out;
    float* zq   = out;                     // [nrows * E_DIM]
    float* loss = out + zsz;               // [2]
    float* idxf = out + zsz + 2;           // [nrows] as float values

    short* img = (short*)d_ws;             // 1 MB: 64 chunk images, 16 KB each

    hipMemsetAsync(loss, 0, 2 * sizeof(float), stream);

    vq_prep<<<dim3(128), 256, 0, stream>>>(emb, img);
    vq_kernel<<<dim3(nrows / BM), NT, 0, stream>>>(
        z, emb, img, zq, loss, idxf, 1.0f / ((float)nrows * (float)E_DIM));
}